// Round 1
// baseline (223.035 us; speedup 1.0000x reference)
//
#include <hip/hip_runtime.h>
#include <cstdint>
#include <cstddef>

// Problem: B=32, S=512, D=768, K=3
// logits = concat(hidden,wsub) @ (W_cnn@W_dense) + (b_cnn@W_dense + b_dense)
// then CRF forward (log-norm) + unary/binary score + Viterbi decode.
//
// ws layout (floats):
//   [0,    4608)  Weff (1536 x 3)
//   [4608, 4611)  beff (3)
//   [4624, 53776) logits (32*512*3)

#define NROW 16384   // B*S
#define DF   768
#define DX   1536

__device__ __forceinline__ float lse3(float x, float y, float z) {
  float m = fmaxf(x, fmaxf(y, z));
  return m + __logf(__expf(x - m) + __expf(y - m) + __expf(z - m));
}

__device__ __forceinline__ unsigned long long shfl_u64(unsigned long long v, int src) {
  int lo = __shfl((int)(unsigned int)(v & 0xffffffffULL), src, 64);
  int hi = __shfl((int)(unsigned int)(v >> 32), src, 64);
  return ((unsigned long long)(unsigned int)hi << 32) | (unsigned long long)(unsigned int)lo;
}

// ---------- Kernel A: collapse weights ----------
// grid 1537 x block 64. Row r<1536: Weff[r][k] = sum_f Wc[r][f]*Wd[f][k].
// Row 1536: beff[k] = sum_f bc[f]*Wd[f][k] + bd[k].
__global__ __launch_bounds__(64) void k_weff(
    const float* __restrict__ Wc, const float* __restrict__ bc,
    const float* __restrict__ Wd, const float* __restrict__ bd,
    float* __restrict__ Weff, float* __restrict__ beff) {
  int r = blockIdx.x;
  int lane = threadIdx.x;
  const float* src = (r < DX) ? (Wc + (size_t)r * DF) : bc;
  float a0 = 0.f, a1 = 0.f, a2 = 0.f;
  for (int f = lane; f < DF; f += 64) {
    float w = src[f];
    const float* wd = Wd + f * 3;
    a0 += w * wd[0]; a1 += w * wd[1]; a2 += w * wd[2];
  }
  for (int off = 32; off; off >>= 1) {
    a0 += __shfl_xor(a0, off);
    a1 += __shfl_xor(a1, off);
    a2 += __shfl_xor(a2, off);
  }
  if (lane == 0) {
    if (r < DX) {
      Weff[r * 3 + 0] = a0; Weff[r * 3 + 1] = a1; Weff[r * 3 + 2] = a2;
    } else {
      beff[0] = a0 + bd[0]; beff[1] = a1 + bd[1]; beff[2] = a2 + bd[2];
    }
  }
}

// ---------- Kernel B: logits = x @ Weff + beff ----------
// grid 4096 x block 256 (4 waves). One wave per (b,s) row.
__global__ __launch_bounds__(256) void k_logits(
    const float* __restrict__ hidden, const float* __restrict__ wsub,
    const float* __restrict__ Weff, const float* __restrict__ beff,
    float* __restrict__ logits) {
  int wave = threadIdx.x >> 6;
  int lane = threadIdx.x & 63;
  int row = blockIdx.x * 4 + wave;
  const float4* h4 = (const float4*)(hidden + (size_t)row * DF);
  const float4* s4 = (const float4*)(wsub + (size_t)row * DF);
  float a0 = 0.f, a1 = 0.f, a2 = 0.f;
#pragma unroll
  for (int j = 0; j < 3; ++j) {
    int f4 = lane + 64 * j;              // float4 index in [0,192)
    float4 hv = h4[f4];
    float4 sv = s4[f4];
    const float4* wH = (const float4*)(Weff + (size_t)f4 * 12);
    const float4* wS = (const float4*)(Weff + (size_t)(DF + f4 * 4) * 3);
    float4 h0 = wH[0], h1 = wH[1], h2 = wH[2];
    float4 w0 = wS[0], w1 = wS[1], w2 = wS[2];
    a0 += hv.x * h0.x + hv.y * h0.w + hv.z * h1.z + hv.w * h2.y
        + sv.x * w0.x + sv.y * w0.w + sv.z * w1.z + sv.w * w2.y;
    a1 += hv.x * h0.y + hv.y * h1.x + hv.z * h1.w + hv.w * h2.z
        + sv.x * w0.y + sv.y * w1.x + sv.z * w1.w + sv.w * w2.z;
    a2 += hv.x * h0.z + hv.y * h1.y + hv.z * h2.x + hv.w * h2.w
        + sv.x * w0.z + sv.y * w1.y + sv.z * w2.x + sv.w * w2.w;
  }
  for (int off = 32; off; off >>= 1) {
    a0 += __shfl_xor(a0, off);
    a1 += __shfl_xor(a1, off);
    a2 += __shfl_xor(a2, off);
  }
  if (lane == 0) {
    float* o = logits + (size_t)row * 3;
    o[0] = a0 + beff[0]; o[1] = a1 + beff[1]; o[2] = a2 + beff[2];
  }
}

// ---------- Kernel C: CRF per batch ----------
// grid 32 x block 128 (wave 0: forward LSE + scores; wave 1: Viterbi + backtrace)
__global__ __launch_bounds__(128) void k_crf(
    const float* __restrict__ logits, const float* __restrict__ trans,
    const int* __restrict__ tgt, float* __restrict__ out) {
  __shared__ float slog[512 * 3];
  __shared__ int   stgt[512];
  __shared__ int   stags[512];
  __shared__ float strn[9];

  int b = blockIdx.x;
  int tid = threadIdx.x;
  int lane = tid & 63;
  int wv = tid >> 6;

  // cooperative loads
  {
    const float4* src = (const float4*)(logits + (size_t)b * 1536);
    float4* dst = (float4*)slog;
    for (int i = tid; i < 384; i += 128) dst[i] = src[i];
    const int* ts = tgt + (size_t)b * 512;
    for (int i = tid; i < 512; i += 128) stgt[i] = ts[i];
    if (tid < 9) strn[tid] = trans[tid];
  }
  __syncthreads();

  // seq_len (redundant per wave)
  int cnt = 0;
  for (int i = lane; i < 512; i += 64) cnt += (stgt[i] >= 1) ? 1 : 0;
  for (int off = 32; off; off >>= 1) cnt += __shfl_xor(cnt, off);
  int L = cnt;

  float T00 = strn[0], T01 = strn[1], T02 = strn[2];
  float T10 = strn[3], T11 = strn[4], T12 = strn[5];
  float T20 = strn[6], T21 = strn[7], T22 = strn[8];

  if (wv == 0) {
    // unary + binary partial sums
    float part = 0.f;
    for (int t = lane; t < 512; t += 64) {
      if (t < L)       part += slog[t * 3 + stgt[t]];
      if (t < L - 1)   part += strn[stgt[t] * 3 + stgt[t + 1]];
    }
    for (int off = 32; off; off >>= 1) part += __shfl_xor(part, off);

    // forward logsumexp scan up to idx = clip(L-1, 0, 511)
    float a0 = slog[0], a1 = slog[1], a2 = slog[2];
    int idx = L - 1; idx = idx < 0 ? 0 : (idx > 511 ? 511 : idx);
    for (int t = 1; t <= idx; ++t) {
      float n0 = slog[t * 3 + 0] + lse3(a0 + T00, a1 + T10, a2 + T20);
      float n1 = slog[t * 3 + 1] + lse3(a0 + T01, a1 + T11, a2 + T21);
      float n2 = slog[t * 3 + 2] + lse3(a0 + T02, a1 + T12, a2 + T22);
      a0 = n0; a1 = n1; a2 = n2;
    }
    float log_norm = lse3(a0, a1, a2);
    if (L <= 0) log_norm = 0.f;
    if (lane == 0) out[16384 + b] = part - log_norm;
  } else {
    // Viterbi: backpointers packed 6 bits/step, step t lives in lane (t>>3),
    // bits 6*(t&7) of a per-lane u64.
    float a0 = slog[0], a1 = slog[1], a2 = slog[2];
    unsigned long long mybp = 0ULL;
    for (int t = 1; t < L; ++t) {
      float s0, s1, s2, m0, m1, m2;
      int bp0 = 0, bp1 = 0, bp2 = 0;
      s0 = a0 + T00; s1 = a1 + T10; s2 = a2 + T20;
      m0 = s0; if (s1 > m0) { m0 = s1; bp0 = 1; } if (s2 > m0) { m0 = s2; bp0 = 2; }
      s0 = a0 + T01; s1 = a1 + T11; s2 = a2 + T21;
      m1 = s0; if (s1 > m1) { m1 = s1; bp1 = 1; } if (s2 > m1) { m1 = s2; bp1 = 2; }
      s0 = a0 + T02; s1 = a1 + T12; s2 = a2 + T22;
      m2 = s0; if (s1 > m2) { m2 = s1; bp2 = 1; } if (s2 > m2) { m2 = s2; bp2 = 2; }
      int bpw = bp0 | (bp1 << 2) | (bp2 << 4);
      if (lane == (t >> 3)) mybp |= (unsigned long long)bpw << (6 * (t & 7));
      a0 = slog[t * 3 + 0] + m0;
      a1 = slog[t * 3 + 1] + m1;
      a2 = slog[t * 3 + 2] + m2;
    }
    int init_tag = 0; float mx = a0;
    if (a1 > mx) { mx = a1; init_tag = 1; }
    if (a2 > mx) { mx = a2; init_tag = 2; }

    for (int i = lane; i < 512; i += 64) stags[i] = 0;
    int Lm1 = L - 1;
    if (Lm1 >= 0) {
      int tag = init_tag;
      if (lane == 0) stags[Lm1] = tag;
      for (int t = Lm1 - 1; t >= 0; --t) {
        int src = t + 1;
        unsigned long long w = shfl_u64(mybp, src >> 3);
        int bpw = (int)((w >> (6 * (src & 7))) & 63ULL);
        tag = (bpw >> (2 * tag)) & 3;
        if (lane == 0) stags[t] = tag;
      }
    }
  }
  __syncthreads();
  // tags written as float32 (hedge: harness reads d_out as float32)
  float* otag = out + (size_t)b * 512;
  for (int i = tid; i < 512; i += 128) otag[i] = (float)stags[i];
}

extern "C" void kernel_launch(void* const* d_in, const int* in_sizes, int n_in,
                              void* d_out, int out_size, void* d_ws, size_t ws_size,
                              hipStream_t stream) {
  const float* hidden = (const float*)d_in[0];
  const float* wsub   = (const float*)d_in[1];
  const float* Wc     = (const float*)d_in[2];
  const float* bc     = (const float*)d_in[3];
  const float* Wd     = (const float*)d_in[4];
  const float* bd     = (const float*)d_in[5];
  const float* trans  = (const float*)d_in[6];
  const int*   tgt    = (const int*)d_in[7];

  float* ws     = (float*)d_ws;
  float* Weff   = ws;
  float* beff   = ws + 4608;
  float* logits = ws + 4624;
  float* out    = (float*)d_out;

  hipLaunchKernelGGL(k_weff,   dim3(1537), dim3(64),  0, stream, Wc, bc, Wd, bd, Weff, beff);
  hipLaunchKernelGGL(k_logits, dim3(4096), dim3(256), 0, stream, hidden, wsub, Weff, beff, logits);
  hipLaunchKernelGGL(k_crf,    dim3(32),   dim3(128), 0, stream, logits, trans, tgt, out);
}

// Round 2
// 149.515 us; speedup vs baseline: 1.4917x; 1.4917x over previous
//
#include <hip/hip_runtime.h>
#include <cstdint>
#include <cstddef>

// B=32, S=512, D=768, K=3
// ws layout (floats):
//   [0, 4608)        WeffT (3 x 1536, column-major: WeffT[k*1536 + r])
//   [4608, 4611)     beff (3)
//   [4624, 53776)    logits (32*512*3)

#define DF 768
#define DX 1536
#define NINF 1e30f

__device__ __forceinline__ float lse3(float x, float y, float z) {
  float m = fmaxf(x, fmaxf(y, z));
  return m + __logf(__expf(x - m) + __expf(y - m) + __expf(z - m));
}

// R = A (*) B in (logsumexp,+) semiring; A,B,R are 3x3 row-major
__device__ __forceinline__ void lse_compose(const float* A, const float* B, float* R) {
#pragma unroll
  for (int i = 0; i < 3; ++i)
#pragma unroll
    for (int j = 0; j < 3; ++j)
      R[3 * i + j] = lse3(A[3 * i + 0] + B[0 + j], A[3 * i + 1] + B[3 + j], A[3 * i + 2] + B[6 + j]);
}

// R = A (*) B in (max,+) semiring
__device__ __forceinline__ void max_compose(const float* A, const float* B, float* R) {
#pragma unroll
  for (int i = 0; i < 3; ++i)
#pragma unroll
    for (int j = 0; j < 3; ++j)
      R[3 * i + j] = fmaxf(fmaxf(A[3 * i + 0] + B[0 + j], A[3 * i + 1] + B[3 + j]), A[3 * i + 2] + B[6 + j]);
}

// map composition over {0,1,2}: r(x) = a(b(x)); maps packed 2 bits/entry (6 bits)
__device__ __forceinline__ int map_compose(int a, int b) {
  int r = 0;
#pragma unroll
  for (int j = 0; j < 3; ++j) r |= ((a >> (2 * ((b >> (2 * j)) & 3))) & 3) << (2 * j);
  return r;
}

__device__ __forceinline__ unsigned long long shfl_down_u64(unsigned long long v, int d) {
  int lo = __shfl_down((int)(unsigned int)(v & 0xffffffffULL), d, 64);
  int hi = __shfl_down((int)(unsigned int)(v >> 32), d, 64);
  return ((unsigned long long)(unsigned int)hi << 32) | (unsigned long long)(unsigned int)lo;
}

// ---------- Kernel A: collapse weights (transposed output) ----------
__global__ __launch_bounds__(64) void k_weff(
    const float* __restrict__ Wc, const float* __restrict__ bc,
    const float* __restrict__ Wd, const float* __restrict__ bd,
    float* __restrict__ WeffT, float* __restrict__ beff) {
  int r = blockIdx.x;
  int lane = threadIdx.x;
  const float* src = (r < DX) ? (Wc + (size_t)r * DF) : bc;
  float a0 = 0.f, a1 = 0.f, a2 = 0.f;
  for (int f = lane; f < DF; f += 64) {
    float w = src[f];
    const float* wd = Wd + f * 3;
    a0 += w * wd[0]; a1 += w * wd[1]; a2 += w * wd[2];
  }
#pragma unroll
  for (int off = 32; off; off >>= 1) {
    a0 += __shfl_xor(a0, off, 64);
    a1 += __shfl_xor(a1, off, 64);
    a2 += __shfl_xor(a2, off, 64);
  }
  if (lane == 0) {
    if (r < DX) {
      WeffT[0 * DX + r] = a0; WeffT[1 * DX + r] = a1; WeffT[2 * DX + r] = a2;
    } else {
      beff[0] = a0 + bd[0]; beff[1] = a1 + bd[1]; beff[2] = a2 + bd[2];
    }
  }
}

// ---------- Kernel B: logits = x @ Weff + beff (async LDS staging) ----------
// grid 512 x block 256. Tile = 8 rows (48 KB LDS). Weights register-resident.
__global__ __launch_bounds__(256) void k_logits(
    const float* __restrict__ hidden, const float* __restrict__ wsub,
    const float* __restrict__ WeffT, const float* __restrict__ beff,
    float* __restrict__ logits) {
  __shared__ float smem[8 * 1536];
  const int lane = threadIdx.x & 63;
  const int wv = threadIdx.x >> 6;

  // per-lane weight fragments: wr[k][c] covers slot float4 index (64*c + lane)
  float4 wr[3][6];
  {
    const float4* wt4 = (const float4*)WeffT;
#pragma unroll
    for (int k = 0; k < 3; ++k)
#pragma unroll
      for (int c = 0; c < 6; ++c)
        wr[k][c] = wt4[k * 384 + 64 * c + lane];
  }
  float b0 = beff[0], b1 = beff[1], b2 = beff[2];

  for (int tile = blockIdx.x; tile < 2048; tile += gridDim.x) {
    const int row0 = tile * 8;
    // stage: 48 chunks of 1 KB; wave wv takes chunks [wv*12, wv*12+12)
#pragma unroll
    for (int i = 0; i < 12; ++i) {
      int c = wv * 12 + i;
      int row = c / 6, cr = c % 6;
      int half = cr / 3, part = cr % 3;
      const float* g = (half ? wsub : hidden) + (size_t)(row0 + row) * DF + part * 256 + lane * 4;
      float* l = smem + row * 1536 + half * 768 + part * 256;  // wave-uniform
      __builtin_amdgcn_global_load_lds((const __attribute__((address_space(1))) void*)g,
                                       (__attribute__((address_space(3))) void*)l, 16, 0, 0);
    }
    __builtin_amdgcn_s_waitcnt(0);
    __syncthreads();

#pragma unroll
    for (int rr = 0; rr < 2; ++rr) {
      int r = wv * 2 + rr;
      const float4* slot = (const float4*)(smem + r * 1536);
      float a0 = 0.f, a1 = 0.f, a2 = 0.f;
#pragma unroll
      for (int c = 0; c < 6; ++c) {
        float4 v = slot[64 * c + lane];
        a0 += v.x * wr[0][c].x + v.y * wr[0][c].y + v.z * wr[0][c].z + v.w * wr[0][c].w;
        a1 += v.x * wr[1][c].x + v.y * wr[1][c].y + v.z * wr[1][c].z + v.w * wr[1][c].w;
        a2 += v.x * wr[2][c].x + v.y * wr[2][c].y + v.z * wr[2][c].z + v.w * wr[2][c].w;
      }
#pragma unroll
      for (int s = 32; s; s >>= 1) {
        a0 += __shfl_xor(a0, s, 64);
        a1 += __shfl_xor(a1, s, 64);
        a2 += __shfl_xor(a2, s, 64);
      }
      if (lane == 0) {
        float* o = logits + (size_t)(row0 + r) * 3;
        o[0] = a0 + b0; o[1] = a1 + b1; o[2] = a2 + b2;
      }
    }
    __syncthreads();
  }
}

// ---------- Kernel C: CRF via parallel semiring scan ----------
// grid 32 x block 128. Wave 0: log-likelihood (LSE semiring reduction).
// Wave 1: Viterbi (max-plus Kogge-Stone) + map-composition backtrace.
__global__ __launch_bounds__(128) void k_crf(
    const float* __restrict__ logits, const float* __restrict__ trans,
    const int* __restrict__ tgt, float* __restrict__ out) {
  const int b = blockIdx.x;
  const int lane = threadIdx.x & 63;
  const int wv = threadIdx.x >> 6;
  const float* lrow = logits + (size_t)b * 1536;

  // lane owns positions t in [8*lane, 8*lane+8)
  float lg[24];
  {
    const float4* l4 = (const float4*)(lrow + lane * 24);
#pragma unroll
    for (int i = 0; i < 6; ++i) {
      float4 v = l4[i];
      lg[4 * i + 0] = v.x; lg[4 * i + 1] = v.y; lg[4 * i + 2] = v.z; lg[4 * i + 3] = v.w;
    }
  }
  int tl[8];
  {
    const int4* t4 = (const int4*)(tgt + (size_t)b * 512 + lane * 8);
    int4 u = t4[0], v = t4[1];
    tl[0] = u.x; tl[1] = u.y; tl[2] = u.z; tl[3] = u.w;
    tl[4] = v.x; tl[5] = v.y; tl[6] = v.z; tl[7] = v.w;
  }
  int cnt = 0;
#pragma unroll
  for (int j = 0; j < 8; ++j) cnt += (tl[j] >= 1) ? 1 : 0;
#pragma unroll
  for (int s = 32; s; s >>= 1) cnt += __shfl_xor(cnt, s, 64);
  const int L = cnt;

  float T[9];
#pragma unroll
  for (int i = 0; i < 9; ++i) T[i] = trans[i];
  float f0 = lrow[0], f1 = lrow[1], f2 = lrow[2];

  if (wv == 0) {
    // unary + binary
    float part = 0.f;
    int tln = __shfl_down(tl[0], 1, 64);
#pragma unroll
    for (int j = 0; j < 8; ++j) {
      int t = 8 * lane + j;
      if (t < L) part += lg[3 * j + tl[j]];
      int nxt = (j < 7) ? tl[j + 1] : tln;
      if (t < L - 1) part += T[3 * tl[j] + nxt];
    }
#pragma unroll
    for (int s = 32; s; s >>= 1) part += __shfl_xor(part, s, 64);

    // log_norm: ordered product of step matrices t in [1, idx]
    int idx = L - 1; if (idx < 0) idx = 0;
    float C[9] = {0.f, -NINF, -NINF, -NINF, 0.f, -NINF, -NINF, -NINF, 0.f};
#pragma unroll
    for (int j = 0; j < 8; ++j) {
      int t = 8 * lane + j;
      if (t >= 1 && t <= idx) {
        float M[9], R[9];
#pragma unroll
        for (int i = 0; i < 3; ++i)
#pragma unroll
          for (int k = 0; k < 3; ++k) M[3 * i + k] = T[3 * i + k] + lg[3 * j + k];
        lse_compose(C, M, R);
#pragma unroll
        for (int i = 0; i < 9; ++i) C[i] = R[i];
      }
    }
    // ordered butterfly reduction (non-commutative: min-index operand on the left)
#pragma unroll
    for (int s = 1; s < 64; s <<= 1) {
      float D[9], A[9], Bm[9], R[9];
#pragma unroll
      for (int i = 0; i < 9; ++i) D[i] = __shfl_xor(C[i], s, 64);
      bool hi = (lane & s) != 0;
#pragma unroll
      for (int i = 0; i < 9; ++i) { A[i] = hi ? D[i] : C[i]; Bm[i] = hi ? C[i] : D[i]; }
      lse_compose(A, Bm, R);
#pragma unroll
      for (int i = 0; i < 9; ++i) C[i] = R[i];
    }
    float al0 = lse3(f0 + C[0], f1 + C[3], f2 + C[6]);
    float al1 = lse3(f0 + C[1], f1 + C[4], f2 + C[7]);
    float al2 = lse3(f0 + C[2], f1 + C[5], f2 + C[8]);
    float log_norm = lse3(al0, al1, al2);
    if (L <= 0) log_norm = 0.f;
    if (lane == 0) out[16384 + b] = part - log_norm;
  } else {
    // ---- Viterbi ----
    // local ordered (max,+) product over steps t in [1, L) owned by this lane
    float P[9] = {0.f, -NINF, -NINF, -NINF, 0.f, -NINF, -NINF, -NINF, 0.f};
#pragma unroll
    for (int j = 0; j < 8; ++j) {
      int t = 8 * lane + j;
      if (t >= 1 && t < L) {
        float M[9], R[9];
#pragma unroll
        for (int i = 0; i < 3; ++i)
#pragma unroll
          for (int k = 0; k < 3; ++k) M[3 * i + k] = T[3 * i + k] + lg[3 * j + k];
        max_compose(P, M, R);
#pragma unroll
        for (int i = 0; i < 9; ++i) P[i] = R[i];
      }
    }
    // inclusive Kogge-Stone prefix (ordered: earlier lane on the left)
    float S[9];
#pragma unroll
    for (int i = 0; i < 9; ++i) S[i] = P[i];
#pragma unroll
    for (int s = 1; s < 64; s <<= 1) {
      float D[9];
#pragma unroll
      for (int i = 0; i < 9; ++i) D[i] = __shfl_up(S[i], s, 64);
      if (lane >= s) {
        float R[9];
        max_compose(D, S, R);
#pragma unroll
        for (int i = 0; i < 9; ++i) S[i] = R[i];
      }
    }
    // exclusive product -> alpha entering this lane's first step
    float E[9];
#pragma unroll
    for (int i = 0; i < 9; ++i) E[i] = __shfl_up(S[i], 1, 64);
    if (lane == 0) {
      E[0] = 0.f; E[1] = -NINF; E[2] = -NINF;
      E[3] = -NINF; E[4] = 0.f; E[5] = -NINF;
      E[6] = -NINF; E[7] = -NINF; E[8] = 0.f;
    }
    float a0 = fmaxf(fmaxf(f0 + E[0], f1 + E[3]), f2 + E[6]);
    float a1 = fmaxf(fmaxf(f0 + E[1], f1 + E[4]), f2 + E[7]);
    float a2 = fmaxf(fmaxf(f0 + E[2], f1 + E[5]), f2 + E[8]);

    // per-step backpointers (first-index argmax ties, like jnp.argmax)
    unsigned long long vbp = 0ULL;
#pragma unroll
    for (int j = 0; j < 8; ++j) {
      int t = 8 * lane + j;
      if (t >= 1 && t < L) {
        int bpw = 0;
        float n0, n1, n2;
        {
          int bp = 0; float m = a0 + T[0]; float c1 = a1 + T[3]; if (c1 > m) { m = c1; bp = 1; }
          float c2 = a2 + T[6]; if (c2 > m) { m = c2; bp = 2; }
          n0 = lg[3 * j + 0] + m; bpw |= bp;
        }
        {
          int bp = 0; float m = a0 + T[1]; float c1 = a1 + T[4]; if (c1 > m) { m = c1; bp = 1; }
          float c2 = a2 + T[7]; if (c2 > m) { m = c2; bp = 2; }
          n1 = lg[3 * j + 1] + m; bpw |= bp << 2;
        }
        {
          int bp = 0; float m = a0 + T[2]; float c1 = a1 + T[5]; if (c1 > m) { m = c1; bp = 1; }
          float c2 = a2 + T[8]; if (c2 > m) { m = c2; bp = 2; }
          n2 = lg[3 * j + 2] + m; bpw |= bp << 4;
        }
        a0 = n0; a1 = n1; a2 = n2;
        vbp |= (unsigned long long)bpw << (6 * j);
      }
    }
    // init_tag from final alpha (lane 63 holds alpha_{L-1})
    float g0 = __shfl(a0, 63, 64), g1 = __shfl(a1, 63, 64), g2 = __shfl(a2, 63, 64);
    int init_tag = 0; float mx = g0;
    if (g1 > mx) { mx = g1; init_tag = 1; }
    if (g2 > mx) { mx = g2; init_tag = 2; }

    // backtrace: h_t maps tag_{t+1} -> tag_t; identity (0x24) for t >= L-1
    unsigned long long nb = shfl_down_u64(vbp, 1);
    int ht[8];
#pragma unroll
    for (int j = 0; j < 8; ++j) {
      int t = 8 * lane + j;
      int h = 0x24;
      if (t < L - 1) h = (j < 7) ? (int)((vbp >> (6 * (j + 1))) & 63ULL) : (int)(nb & 63ULL);
      ht[j] = h;
    }
    int F = 0x24;
#pragma unroll
    for (int j = 7; j >= 0; --j) F = map_compose(ht[j], F);
    // suffix Kogge-Stone of maps
    int S2 = F;
#pragma unroll
    for (int s = 1; s < 64; s <<= 1) {
      int D = __shfl_down(S2, s, 64);
      if (lane + s < 64) S2 = map_compose(S2, D);
    }
    int tail = __shfl_down(S2, 1, 64);
    if (lane == 63) tail = 0x24;
    int cur = (tail >> (2 * init_tag)) & 3;  // tag_{8*lane+8}
    int tags[8];
#pragma unroll
    for (int j = 7; j >= 0; --j) {
      cur = (ht[j] >> (2 * cur)) & 3;
      int t = 8 * lane + j;
      tags[j] = (t < L) ? cur : 0;
    }
    float4 o0, o1;
    o0.x = (float)tags[0]; o0.y = (float)tags[1]; o0.z = (float)tags[2]; o0.w = (float)tags[3];
    o1.x = (float)tags[4]; o1.y = (float)tags[5]; o1.z = (float)tags[6]; o1.w = (float)tags[7];
    float4* op = (float4*)(out + (size_t)b * 512 + lane * 8);
    op[0] = o0; op[1] = o1;
  }
}

extern "C" void kernel_launch(void* const* d_in, const int* in_sizes, int n_in,
                              void* d_out, int out_size, void* d_ws, size_t ws_size,
                              hipStream_t stream) {
  const float* hidden = (const float*)d_in[0];
  const float* wsub   = (const float*)d_in[1];
  const float* Wc     = (const float*)d_in[2];
  const float* bc     = (const float*)d_in[3];
  const float* Wd     = (const float*)d_in[4];
  const float* bd     = (const float*)d_in[5];
  const float* trans  = (const float*)d_in[6];
  const int*   tgt    = (const int*)d_in[7];

  float* ws     = (float*)d_ws;
  float* WeffT  = ws;
  float* beff   = ws + 4608;
  float* logits = ws + 4624;
  float* out    = (float*)d_out;

  hipLaunchKernelGGL(k_weff,   dim3(1537), dim3(64),  0, stream, Wc, bc, Wd, bd, WeffT, beff);
  hipLaunchKernelGGL(k_logits, dim3(512),  dim3(256), 0, stream, hidden, wsub, WeffT, beff, logits);
  hipLaunchKernelGGL(k_crf,    dim3(32),   dim3(128), 0, stream, logits, trans, tgt, out);
}

// Round 3
// 145.925 us; speedup vs baseline: 1.5284x; 1.0246x over previous
//
#include <hip/hip_runtime.h>
#include <cstdint>
#include <cstddef>

// B=32, S=512, D=768, K=3
// ws layout (floats):
//   [0, 4608)        WeffT (3 x 1536, column-major: WeffT[k*1536 + r])
//   [4608, 4611)     beff (3)
//   [4624, 53776)    logits (32*512*3)

#define DF 768
#define DX 1536
#define NINF 1e30f

__device__ __forceinline__ float lse3(float x, float y, float z) {
  float m = fmaxf(x, fmaxf(y, z));
  return m + __logf(__expf(x - m) + __expf(y - m) + __expf(z - m));
}

__device__ __forceinline__ void lse_compose(const float* A, const float* B, float* R) {
#pragma unroll
  for (int i = 0; i < 3; ++i)
#pragma unroll
    for (int j = 0; j < 3; ++j)
      R[3 * i + j] = lse3(A[3 * i + 0] + B[0 + j], A[3 * i + 1] + B[3 + j], A[3 * i + 2] + B[6 + j]);
}

__device__ __forceinline__ void max_compose(const float* A, const float* B, float* R) {
#pragma unroll
  for (int i = 0; i < 3; ++i)
#pragma unroll
    for (int j = 0; j < 3; ++j)
      R[3 * i + j] = fmaxf(fmaxf(A[3 * i + 0] + B[0 + j], A[3 * i + 1] + B[3 + j]), A[3 * i + 2] + B[6 + j]);
}

__device__ __forceinline__ int map_compose(int a, int b) {
  int r = 0;
#pragma unroll
  for (int j = 0; j < 3; ++j) r |= ((a >> (2 * ((b >> (2 * j)) & 3))) & 3) << (2 * j);
  return r;
}

__device__ __forceinline__ unsigned long long shfl_down_u64(unsigned long long v, int d) {
  int lo = __shfl_down((int)(unsigned int)(v & 0xffffffffULL), d, 64);
  int hi = __shfl_down((int)(unsigned int)(v >> 32), d, 64);
  return ((unsigned long long)(unsigned int)hi << 32) | (unsigned long long)(unsigned int)lo;
}

// ---------- Kernel A: collapse weights (transposed output) ----------
// grid 385 x block 256; wave per row (1537 rows incl. bias row).
__global__ __launch_bounds__(256) void k_weff(
    const float* __restrict__ Wc, const float* __restrict__ bc,
    const float* __restrict__ Wd, const float* __restrict__ bd,
    float* __restrict__ WeffT, float* __restrict__ beff) {
  int lane = threadIdx.x & 63;
  int wv = threadIdx.x >> 6;
  int r = blockIdx.x * 4 + wv;
  if (r > DX) return;
  const float* src = (r < DX) ? (Wc + (size_t)r * DF) : bc;
  float a0 = 0.f, a1 = 0.f, a2 = 0.f;
#pragma unroll
  for (int it = 0; it < 12; ++it) {
    int f = lane + 64 * it;
    float w = src[f];
    const float* wd = Wd + f * 3;
    a0 += w * wd[0]; a1 += w * wd[1]; a2 += w * wd[2];
  }
#pragma unroll
  for (int off = 32; off; off >>= 1) {
    a0 += __shfl_xor(a0, off, 64);
    a1 += __shfl_xor(a1, off, 64);
    a2 += __shfl_xor(a2, off, 64);
  }
  if (lane == 0) {
    if (r < DX) {
      WeffT[0 * DX + r] = a0; WeffT[1 * DX + r] = a1; WeffT[2 * DX + r] = a2;
    } else {
      beff[0] = a0 + bd[0]; beff[1] = a1 + bd[1]; beff[2] = a2 + bd[2];
    }
  }
}

// ---------- Kernel B: logits, wave-private double-buffered LDS pipeline ----------
// grid 512 x block 256 (4 waves). Wave handles 8 rows (pass-strided), staging
// its own row via global_load_lds into its private 2x6KB buffers. No barriers
// in the loop -> no vmcnt(0) drain; HBM streams continuously.
__global__ __launch_bounds__(256) void k_logits(
    const float* __restrict__ hidden, const float* __restrict__ wsub,
    const float* __restrict__ WeffT, const float* __restrict__ beff,
    float* __restrict__ logits) {
  __shared__ float smem[4 * 2 * 1536];  // 48 KB: wave wv buffer b at (wv*2+b)*1536
  const int lane = threadIdx.x & 63;
  const int wv = threadIdx.x >> 6;

  // weights register-resident: wr[k][c] covers float4 slot (64*c + lane)
  float4 wr[3][6];
  {
    const float4* wt4 = (const float4*)WeffT;
#pragma unroll
    for (int k = 0; k < 3; ++k)
#pragma unroll
      for (int c = 0; c < 6; ++c)
        wr[k][c] = wt4[k * 384 + 64 * c + lane];
  }
  const float b0 = beff[0], b1 = beff[1], b2 = beff[2];

  float* mybuf = smem + wv * 3072;
  const int slot = blockIdx.x * 4 + wv;   // wave slot in [0, 2048)

#define STAGE(ROW, BUF)                                                              \
  do {                                                                               \
    const float* hsrc_ = hidden + (size_t)(ROW)*DF + lane * 4;                       \
    const float* ssrc_ = wsub + (size_t)(ROW)*DF + lane * 4;                         \
    float* l_ = mybuf + (BUF)*1536;                                                  \
    _Pragma("unroll")                                                                \
    for (int c_ = 0; c_ < 3; ++c_) {                                                 \
      __builtin_amdgcn_global_load_lds(                                              \
          (const __attribute__((address_space(1))) void*)(hsrc_ + c_ * 256),         \
          (__attribute__((address_space(3))) void*)(l_ + c_ * 256), 16, 0, 0);       \
      __builtin_amdgcn_global_load_lds(                                              \
          (const __attribute__((address_space(1))) void*)(ssrc_ + c_ * 256),         \
          (__attribute__((address_space(3))) void*)(l_ + 768 + c_ * 256), 16, 0, 0); \
    }                                                                                \
  } while (0)

  STAGE(slot, 0);
#pragma unroll
  for (int p = 0; p < 8; ++p) {
    if (p < 7) {
      STAGE(slot + (p + 1) * 2048, (p + 1) & 1);
      __builtin_amdgcn_s_waitcnt(0xF76);  // vmcnt(6): prior row's 6 loads done
    } else {
      __builtin_amdgcn_s_waitcnt(0xF70);  // vmcnt(0)
    }
    __builtin_amdgcn_sched_barrier(0);    // keep ds_reads after the wait
    const float4* xb = (const float4*)(mybuf + (p & 1) * 1536);
    float a0 = 0.f, a1 = 0.f, a2 = 0.f;
#pragma unroll
    for (int c = 0; c < 6; ++c) {
      float4 v = xb[64 * c + lane];
      a0 += v.x * wr[0][c].x + v.y * wr[0][c].y + v.z * wr[0][c].z + v.w * wr[0][c].w;
      a1 += v.x * wr[1][c].x + v.y * wr[1][c].y + v.z * wr[1][c].z + v.w * wr[1][c].w;
      a2 += v.x * wr[2][c].x + v.y * wr[2][c].y + v.z * wr[2][c].z + v.w * wr[2][c].w;
    }
#pragma unroll
    for (int s = 32; s; s >>= 1) {
      a0 += __shfl_xor(a0, s, 64);
      a1 += __shfl_xor(a1, s, 64);
      a2 += __shfl_xor(a2, s, 64);
    }
    if (lane == 0) {
      float* o = logits + (size_t)(slot + p * 2048) * 3;
      o[0] = a0 + b0; o[1] = a1 + b1; o[2] = a2 + b2;
    }
  }
#undef STAGE
}

// ---------- Kernel C: CRF via parallel semiring scan (unchanged, proven) ----------
__global__ __launch_bounds__(128) void k_crf(
    const float* __restrict__ logits, const float* __restrict__ trans,
    const int* __restrict__ tgt, float* __restrict__ out) {
  const int b = blockIdx.x;
  const int lane = threadIdx.x & 63;
  const int wv = threadIdx.x >> 6;
  const float* lrow = logits + (size_t)b * 1536;

  float lg[24];
  {
    const float4* l4 = (const float4*)(lrow + lane * 24);
#pragma unroll
    for (int i = 0; i < 6; ++i) {
      float4 v = l4[i];
      lg[4 * i + 0] = v.x; lg[4 * i + 1] = v.y; lg[4 * i + 2] = v.z; lg[4 * i + 3] = v.w;
    }
  }
  int tl[8];
  {
    const int4* t4 = (const int4*)(tgt + (size_t)b * 512 + lane * 8);
    int4 u = t4[0], v = t4[1];
    tl[0] = u.x; tl[1] = u.y; tl[2] = u.z; tl[3] = u.w;
    tl[4] = v.x; tl[5] = v.y; tl[6] = v.z; tl[7] = v.w;
  }
  int cnt = 0;
#pragma unroll
  for (int j = 0; j < 8; ++j) cnt += (tl[j] >= 1) ? 1 : 0;
#pragma unroll
  for (int s = 32; s; s >>= 1) cnt += __shfl_xor(cnt, s, 64);
  const int L = cnt;

  float T[9];
#pragma unroll
  for (int i = 0; i < 9; ++i) T[i] = trans[i];
  float f0 = lrow[0], f1 = lrow[1], f2 = lrow[2];

  if (wv == 0) {
    float part = 0.f;
    int tln = __shfl_down(tl[0], 1, 64);
#pragma unroll
    for (int j = 0; j < 8; ++j) {
      int t = 8 * lane + j;
      if (t < L) part += lg[3 * j + tl[j]];
      int nxt = (j < 7) ? tl[j + 1] : tln;
      if (t < L - 1) part += T[3 * tl[j] + nxt];
    }
#pragma unroll
    for (int s = 32; s; s >>= 1) part += __shfl_xor(part, s, 64);

    int idx = L - 1; if (idx < 0) idx = 0;
    float C[9] = {0.f, -NINF, -NINF, -NINF, 0.f, -NINF, -NINF, -NINF, 0.f};
#pragma unroll
    for (int j = 0; j < 8; ++j) {
      int t = 8 * lane + j;
      if (t >= 1 && t <= idx) {
        float M[9], R[9];
#pragma unroll
        for (int i = 0; i < 3; ++i)
#pragma unroll
          for (int k = 0; k < 3; ++k) M[3 * i + k] = T[3 * i + k] + lg[3 * j + k];
        lse_compose(C, M, R);
#pragma unroll
        for (int i = 0; i < 9; ++i) C[i] = R[i];
      }
    }
#pragma unroll
    for (int s = 1; s < 64; s <<= 1) {
      float D[9], A[9], Bm[9], R[9];
#pragma unroll
      for (int i = 0; i < 9; ++i) D[i] = __shfl_xor(C[i], s, 64);
      bool hi = (lane & s) != 0;
#pragma unroll
      for (int i = 0; i < 9; ++i) { A[i] = hi ? D[i] : C[i]; Bm[i] = hi ? C[i] : D[i]; }
      lse_compose(A, Bm, R);
#pragma unroll
      for (int i = 0; i < 9; ++i) C[i] = R[i];
    }
    float al0 = lse3(f0 + C[0], f1 + C[3], f2 + C[6]);
    float al1 = lse3(f0 + C[1], f1 + C[4], f2 + C[7]);
    float al2 = lse3(f0 + C[2], f1 + C[5], f2 + C[8]);
    float log_norm = lse3(al0, al1, al2);
    if (L <= 0) log_norm = 0.f;
    if (lane == 0) out[16384 + b] = part - log_norm;
  } else {
    float P[9] = {0.f, -NINF, -NINF, -NINF, 0.f, -NINF, -NINF, -NINF, 0.f};
#pragma unroll
    for (int j = 0; j < 8; ++j) {
      int t = 8 * lane + j;
      if (t >= 1 && t < L) {
        float M[9], R[9];
#pragma unroll
        for (int i = 0; i < 3; ++i)
#pragma unroll
          for (int k = 0; k < 3; ++k) M[3 * i + k] = T[3 * i + k] + lg[3 * j + k];
        max_compose(P, M, R);
#pragma unroll
        for (int i = 0; i < 9; ++i) P[i] = R[i];
      }
    }
    float S[9];
#pragma unroll
    for (int i = 0; i < 9; ++i) S[i] = P[i];
#pragma unroll
    for (int s = 1; s < 64; s <<= 1) {
      float D[9];
#pragma unroll
      for (int i = 0; i < 9; ++i) D[i] = __shfl_up(S[i], s, 64);
      if (lane >= s) {
        float R[9];
        max_compose(D, S, R);
#pragma unroll
        for (int i = 0; i < 9; ++i) S[i] = R[i];
      }
    }
    float E[9];
#pragma unroll
    for (int i = 0; i < 9; ++i) E[i] = __shfl_up(S[i], 1, 64);
    if (lane == 0) {
      E[0] = 0.f; E[1] = -NINF; E[2] = -NINF;
      E[3] = -NINF; E[4] = 0.f; E[5] = -NINF;
      E[6] = -NINF; E[7] = -NINF; E[8] = 0.f;
    }
    float a0 = fmaxf(fmaxf(f0 + E[0], f1 + E[3]), f2 + E[6]);
    float a1 = fmaxf(fmaxf(f0 + E[1], f1 + E[4]), f2 + E[7]);
    float a2 = fmaxf(fmaxf(f0 + E[2], f1 + E[5]), f2 + E[8]);

    unsigned long long vbp = 0ULL;
#pragma unroll
    for (int j = 0; j < 8; ++j) {
      int t = 8 * lane + j;
      if (t >= 1 && t < L) {
        int bpw = 0;
        float n0, n1, n2;
        {
          int bp = 0; float m = a0 + T[0]; float c1 = a1 + T[3]; if (c1 > m) { m = c1; bp = 1; }
          float c2 = a2 + T[6]; if (c2 > m) { m = c2; bp = 2; }
          n0 = lg[3 * j + 0] + m; bpw |= bp;
        }
        {
          int bp = 0; float m = a0 + T[1]; float c1 = a1 + T[4]; if (c1 > m) { m = c1; bp = 1; }
          float c2 = a2 + T[7]; if (c2 > m) { m = c2; bp = 2; }
          n1 = lg[3 * j + 1] + m; bpw |= bp << 2;
        }
        {
          int bp = 0; float m = a0 + T[2]; float c1 = a1 + T[5]; if (c1 > m) { m = c1; bp = 1; }
          float c2 = a2 + T[8]; if (c2 > m) { m = c2; bp = 2; }
          n2 = lg[3 * j + 2] + m; bpw |= bp << 4;
        }
        a0 = n0; a1 = n1; a2 = n2;
        vbp |= (unsigned long long)bpw << (6 * j);
      }
    }
    float g0 = __shfl(a0, 63, 64), g1 = __shfl(a1, 63, 64), g2 = __shfl(a2, 63, 64);
    int init_tag = 0; float mx = g0;
    if (g1 > mx) { mx = g1; init_tag = 1; }
    if (g2 > mx) { mx = g2; init_tag = 2; }

    unsigned long long nb = shfl_down_u64(vbp, 1);
    int ht[8];
#pragma unroll
    for (int j = 0; j < 8; ++j) {
      int t = 8 * lane + j;
      int h = 0x24;
      if (t < L - 1) h = (j < 7) ? (int)((vbp >> (6 * (j + 1))) & 63ULL) : (int)(nb & 63ULL);
      ht[j] = h;
    }
    int F = 0x24;
#pragma unroll
    for (int j = 7; j >= 0; --j) F = map_compose(ht[j], F);
    int S2 = F;
#pragma unroll
    for (int s = 1; s < 64; s <<= 1) {
      int D = __shfl_down(S2, s, 64);
      if (lane + s < 64) S2 = map_compose(S2, D);
    }
    int tail = __shfl_down(S2, 1, 64);
    if (lane == 63) tail = 0x24;
    int cur = (tail >> (2 * init_tag)) & 3;
    int tags[8];
#pragma unroll
    for (int j = 7; j >= 0; --j) {
      cur = (ht[j] >> (2 * cur)) & 3;
      int t = 8 * lane + j;
      tags[j] = (t < L) ? cur : 0;
    }
    float4 o0, o1;
    o0.x = (float)tags[0]; o0.y = (float)tags[1]; o0.z = (float)tags[2]; o0.w = (float)tags[3];
    o1.x = (float)tags[4]; o1.y = (float)tags[5]; o1.z = (float)tags[6]; o1.w = (float)tags[7];
    float4* op = (float4*)(out + (size_t)b * 512 + lane * 8);
    op[0] = o0; op[1] = o1;
  }
}

extern "C" void kernel_launch(void* const* d_in, const int* in_sizes, int n_in,
                              void* d_out, int out_size, void* d_ws, size_t ws_size,
                              hipStream_t stream) {
  const float* hidden = (const float*)d_in[0];
  const float* wsub   = (const float*)d_in[1];
  const float* Wc     = (const float*)d_in[2];
  const float* bc     = (const float*)d_in[3];
  const float* Wd     = (const float*)d_in[4];
  const float* bd     = (const float*)d_in[5];
  const float* trans  = (const float*)d_in[6];
  const int*   tgt    = (const int*)d_in[7];

  float* ws     = (float*)d_ws;
  float* WeffT  = ws;
  float* beff   = ws + 4608;
  float* logits = ws + 4624;
  float* out    = (float*)d_out;

  hipLaunchKernelGGL(k_weff,   dim3(385), dim3(256), 0, stream, Wc, bc, Wd, bd, WeffT, beff);
  hipLaunchKernelGGL(k_logits, dim3(512), dim3(256), 0, stream, hidden, wsub, WeffT, beff, logits);
  hipLaunchKernelGGL(k_crf,    dim3(32),  dim3(128), 0, stream, logits, trans, tgt, out);
}

// Round 4
// 144.682 us; speedup vs baseline: 1.5415x; 1.0086x over previous
//
#include <hip/hip_runtime.h>
#include <cstdint>
#include <cstddef>

// B=32, S=512, D=768, K=3
// ws layout (floats):
//   [0, 4608)        WeffT (3 x 1536, column-major: WeffT[k*1536 + r])
//   [4608, 4611)     beff (3)
//   [4624, 53776)    logits (32*512*3)

#define DF 768
#define DX 1536
#define NINF 1e30f

__device__ __forceinline__ float lse3(float x, float y, float z) {
  float m = fmaxf(x, fmaxf(y, z));
  return m + __logf(__expf(x - m) + __expf(y - m) + __expf(z - m));
}

__device__ __forceinline__ void lse_compose(const float* A, const float* B, float* R) {
#pragma unroll
  for (int i = 0; i < 3; ++i)
#pragma unroll
    for (int j = 0; j < 3; ++j)
      R[3 * i + j] = lse3(A[3 * i + 0] + B[0 + j], A[3 * i + 1] + B[3 + j], A[3 * i + 2] + B[6 + j]);
}

__device__ __forceinline__ void max_compose(const float* A, const float* B, float* R) {
#pragma unroll
  for (int i = 0; i < 3; ++i)
#pragma unroll
    for (int j = 0; j < 3; ++j)
      R[3 * i + j] = fmaxf(fmaxf(A[3 * i + 0] + B[0 + j], A[3 * i + 1] + B[3 + j]), A[3 * i + 2] + B[6 + j]);
}

__device__ __forceinline__ int map_compose(int a, int b) {
  int r = 0;
#pragma unroll
  for (int j = 0; j < 3; ++j) r |= ((a >> (2 * ((b >> (2 * j)) & 3))) & 3) << (2 * j);
  return r;
}

// select x[k] for k in {0,1,2} without dynamic indexing (v_cndmask chain)
__device__ __forceinline__ float sel3(int k, float x0, float x1, float x2) {
  return (k == 1) ? x1 : ((k == 2) ? x2 : x0);
}

__device__ __forceinline__ unsigned long long shfl_down_u64(unsigned long long v, int d) {
  int lo = __shfl_down((int)(unsigned int)(v & 0xffffffffULL), d, 64);
  int hi = __shfl_down((int)(unsigned int)(v >> 32), d, 64);
  return ((unsigned long long)(unsigned int)hi << 32) | (unsigned long long)(unsigned int)lo;
}

// ---------- Kernel A: collapse weights (transposed output) ----------
__global__ __launch_bounds__(256) void k_weff(
    const float* __restrict__ Wc, const float* __restrict__ bc,
    const float* __restrict__ Wd, const float* __restrict__ bd,
    float* __restrict__ WeffT, float* __restrict__ beff) {
  int lane = threadIdx.x & 63;
  int wv = threadIdx.x >> 6;
  int r = blockIdx.x * 4 + wv;
  if (r > DX) return;
  const float* src = (r < DX) ? (Wc + (size_t)r * DF) : bc;
  float a0 = 0.f, a1 = 0.f, a2 = 0.f;
#pragma unroll
  for (int it = 0; it < 12; ++it) {
    int f = lane + 64 * it;
    float w = src[f];
    const float* wd = Wd + f * 3;
    a0 += w * wd[0]; a1 += w * wd[1]; a2 += w * wd[2];
  }
#pragma unroll
  for (int off = 32; off; off >>= 1) {
    a0 += __shfl_xor(a0, off, 64);
    a1 += __shfl_xor(a1, off, 64);
    a2 += __shfl_xor(a2, off, 64);
  }
  if (lane == 0) {
    if (r < DX) {
      WeffT[0 * DX + r] = a0; WeffT[1 * DX + r] = a1; WeffT[2 * DX + r] = a2;
    } else {
      beff[0] = a0 + bd[0]; beff[1] = a1 + bd[1]; beff[2] = a2 + bd[2];
    }
  }
}

// ---------- Kernel B: logits, wave-private double-buffered LDS pipeline ----------
__global__ __launch_bounds__(256) void k_logits(
    const float* __restrict__ hidden, const float* __restrict__ wsub,
    const float* __restrict__ WeffT, const float* __restrict__ beff,
    float* __restrict__ logits) {
  __shared__ float smem[4 * 2 * 1536];  // 48 KB
  const int lane = threadIdx.x & 63;
  const int wv = threadIdx.x >> 6;

  float4 wr[3][6];
  {
    const float4* wt4 = (const float4*)WeffT;
#pragma unroll
    for (int k = 0; k < 3; ++k)
#pragma unroll
      for (int c = 0; c < 6; ++c)
        wr[k][c] = wt4[k * 384 + 64 * c + lane];
  }
  const float b0 = beff[0], b1 = beff[1], b2 = beff[2];

  float* mybuf = smem + wv * 3072;
  const int slot = blockIdx.x * 4 + wv;

#define STAGE(ROW, BUF)                                                              \
  do {                                                                               \
    const float* hsrc_ = hidden + (size_t)(ROW)*DF + lane * 4;                       \
    const float* ssrc_ = wsub + (size_t)(ROW)*DF + lane * 4;                         \
    float* l_ = mybuf + (BUF)*1536;                                                  \
    _Pragma("unroll")                                                                \
    for (int c_ = 0; c_ < 3; ++c_) {                                                 \
      __builtin_amdgcn_global_load_lds(                                              \
          (const __attribute__((address_space(1))) void*)(hsrc_ + c_ * 256),         \
          (__attribute__((address_space(3))) void*)(l_ + c_ * 256), 16, 0, 0);       \
      __builtin_amdgcn_global_load_lds(                                              \
          (const __attribute__((address_space(1))) void*)(ssrc_ + c_ * 256),         \
          (__attribute__((address_space(3))) void*)(l_ + 768 + c_ * 256), 16, 0, 0); \
    }                                                                                \
  } while (0)

  STAGE(slot, 0);
#pragma unroll
  for (int p = 0; p < 8; ++p) {
    if (p < 7) {
      STAGE(slot + (p + 1) * 2048, (p + 1) & 1);
      __builtin_amdgcn_s_waitcnt(0xF76);  // vmcnt(6)
    } else {
      __builtin_amdgcn_s_waitcnt(0xF70);  // vmcnt(0)
    }
    __builtin_amdgcn_sched_barrier(0);
    const float4* xb = (const float4*)(mybuf + (p & 1) * 1536);
    float a0 = 0.f, a1 = 0.f, a2 = 0.f;
#pragma unroll
    for (int c = 0; c < 6; ++c) {
      float4 v = xb[64 * c + lane];
      a0 += v.x * wr[0][c].x + v.y * wr[0][c].y + v.z * wr[0][c].z + v.w * wr[0][c].w;
      a1 += v.x * wr[1][c].x + v.y * wr[1][c].y + v.z * wr[1][c].z + v.w * wr[1][c].w;
      a2 += v.x * wr[2][c].x + v.y * wr[2][c].y + v.z * wr[2][c].z + v.w * wr[2][c].w;
    }
#pragma unroll
    for (int s = 32; s; s >>= 1) {
      a0 += __shfl_xor(a0, s, 64);
      a1 += __shfl_xor(a1, s, 64);
      a2 += __shfl_xor(a2, s, 64);
    }
    if (lane == 0) {
      float* o = logits + (size_t)(slot + p * 2048) * 3;
      o[0] = a0 + b0; o[1] = a1 + b1; o[2] = a2 + b2;
    }
  }
#undef STAGE
}

// ---------- Kernel C: CRF parallel semiring scan, spill-free ----------
// grid 32 x block 128. No dynamic local-array indexing anywhere: all runtime
// gathers (unary logit, transition score) go through v_cndmask select chains
// so lg/T/C/S stay in VGPRs (R3 had VGPR_Count=36 => scratch-spilled).
__global__ __launch_bounds__(128) void k_crf(
    const float* __restrict__ logits, const float* __restrict__ trans,
    const int* __restrict__ tgt, float* __restrict__ out) {
  const int b = blockIdx.x;
  const int lane = threadIdx.x & 63;
  const int wv = threadIdx.x >> 6;
  const float* lrow = logits + (size_t)b * 1536;

  float lg[24];
  {
    const float4* l4 = (const float4*)(lrow + lane * 24);
#pragma unroll
    for (int i = 0; i < 6; ++i) {
      float4 v = l4[i];
      lg[4 * i + 0] = v.x; lg[4 * i + 1] = v.y; lg[4 * i + 2] = v.z; lg[4 * i + 3] = v.w;
    }
  }
  int tl[8];
  {
    const int4* t4 = (const int4*)(tgt + (size_t)b * 512 + lane * 8);
    int4 u = t4[0], v = t4[1];
    tl[0] = u.x; tl[1] = u.y; tl[2] = u.z; tl[3] = u.w;
    tl[4] = v.x; tl[5] = v.y; tl[6] = v.z; tl[7] = v.w;
  }
  int cnt = 0;
#pragma unroll
  for (int j = 0; j < 8; ++j) cnt += (tl[j] >= 1) ? 1 : 0;
#pragma unroll
  for (int s = 32; s; s >>= 1) cnt += __shfl_xor(cnt, s, 64);
  const int L = cnt;

  float T[9];
#pragma unroll
  for (int i = 0; i < 9; ++i) T[i] = trans[i];
  float f0 = lrow[0], f1 = lrow[1], f2 = lrow[2];

  if (wv == 0) {
    // unary + binary partial sums — select chains, no dynamic indexing
    float part = 0.f;
    int tln = __shfl_down(tl[0], 1, 64);
#pragma unroll
    for (int j = 0; j < 8; ++j) {
      int t = 8 * lane + j;
      int tj = tl[j];
      float u = sel3(tj, lg[3 * j + 0], lg[3 * j + 1], lg[3 * j + 2]);
      if (t < L) part += u;
      int nxt = (j < 7) ? tl[j + 1] : tln;
      float r0 = sel3(tj, T[0], T[3], T[6]);
      float r1 = sel3(tj, T[1], T[4], T[7]);
      float r2 = sel3(tj, T[2], T[5], T[8]);
      float bsc = sel3(nxt, r0, r1, r2);
      if (t < L - 1) part += bsc;
    }
#pragma unroll
    for (int s = 32; s; s >>= 1) part += __shfl_xor(part, s, 64);

    int idx = L - 1; if (idx < 0) idx = 0;
    float C[9] = {0.f, -NINF, -NINF, -NINF, 0.f, -NINF, -NINF, -NINF, 0.f};
#pragma unroll
    for (int j = 0; j < 8; ++j) {
      int t = 8 * lane + j;
      if (t >= 1 && t <= idx) {
        float M[9], R[9];
#pragma unroll
        for (int i = 0; i < 3; ++i)
#pragma unroll
          for (int k = 0; k < 3; ++k) M[3 * i + k] = T[3 * i + k] + lg[3 * j + k];
        lse_compose(C, M, R);
#pragma unroll
        for (int i = 0; i < 9; ++i) C[i] = R[i];
      }
    }
#pragma unroll
    for (int s = 1; s < 64; s <<= 1) {
      float D[9], A[9], Bm[9], R[9];
#pragma unroll
      for (int i = 0; i < 9; ++i) D[i] = __shfl_xor(C[i], s, 64);
      bool hi = (lane & s) != 0;
#pragma unroll
      for (int i = 0; i < 9; ++i) { A[i] = hi ? D[i] : C[i]; Bm[i] = hi ? C[i] : D[i]; }
      lse_compose(A, Bm, R);
#pragma unroll
      for (int i = 0; i < 9; ++i) C[i] = R[i];
    }
    float al0 = lse3(f0 + C[0], f1 + C[3], f2 + C[6]);
    float al1 = lse3(f0 + C[1], f1 + C[4], f2 + C[7]);
    float al2 = lse3(f0 + C[2], f1 + C[5], f2 + C[8]);
    float log_norm = lse3(al0, al1, al2);
    if (L <= 0) log_norm = 0.f;
    if (lane == 0) out[16384 + b] = part - log_norm;
  } else {
    float P[9] = {0.f, -NINF, -NINF, -NINF, 0.f, -NINF, -NINF, -NINF, 0.f};
#pragma unroll
    for (int j = 0; j < 8; ++j) {
      int t = 8 * lane + j;
      if (t >= 1 && t < L) {
        float M[9], R[9];
#pragma unroll
        for (int i = 0; i < 3; ++i)
#pragma unroll
          for (int k = 0; k < 3; ++k) M[3 * i + k] = T[3 * i + k] + lg[3 * j + k];
        max_compose(P, M, R);
#pragma unroll
        for (int i = 0; i < 9; ++i) P[i] = R[i];
      }
    }
    float S[9];
#pragma unroll
    for (int i = 0; i < 9; ++i) S[i] = P[i];
#pragma unroll
    for (int s = 1; s < 64; s <<= 1) {
      float D[9];
#pragma unroll
      for (int i = 0; i < 9; ++i) D[i] = __shfl_up(S[i], s, 64);
      if (lane >= s) {
        float R[9];
        max_compose(D, S, R);
#pragma unroll
        for (int i = 0; i < 9; ++i) S[i] = R[i];
      }
    }
    float E[9];
#pragma unroll
    for (int i = 0; i < 9; ++i) E[i] = __shfl_up(S[i], 1, 64);
    if (lane == 0) {
      E[0] = 0.f; E[1] = -NINF; E[2] = -NINF;
      E[3] = -NINF; E[4] = 0.f; E[5] = -NINF;
      E[6] = -NINF; E[7] = -NINF; E[8] = 0.f;
    }
    float a0 = fmaxf(fmaxf(f0 + E[0], f1 + E[3]), f2 + E[6]);
    float a1 = fmaxf(fmaxf(f0 + E[1], f1 + E[4]), f2 + E[7]);
    float a2 = fmaxf(fmaxf(f0 + E[2], f1 + E[5]), f2 + E[8]);

    unsigned long long vbp = 0ULL;
#pragma unroll
    for (int j = 0; j < 8; ++j) {
      int t = 8 * lane + j;
      if (t >= 1 && t < L) {
        int bpw = 0;
        float n0, n1, n2;
        {
          int bp = 0; float m = a0 + T[0]; float c1 = a1 + T[3]; if (c1 > m) { m = c1; bp = 1; }
          float c2 = a2 + T[6]; if (c2 > m) { m = c2; bp = 2; }
          n0 = lg[3 * j + 0] + m; bpw |= bp;
        }
        {
          int bp = 0; float m = a0 + T[1]; float c1 = a1 + T[4]; if (c1 > m) { m = c1; bp = 1; }
          float c2 = a2 + T[7]; if (c2 > m) { m = c2; bp = 2; }
          n1 = lg[3 * j + 1] + m; bpw |= bp << 2;
        }
        {
          int bp = 0; float m = a0 + T[2]; float c1 = a1 + T[5]; if (c1 > m) { m = c1; bp = 1; }
          float c2 = a2 + T[8]; if (c2 > m) { m = c2; bp = 2; }
          n2 = lg[3 * j + 2] + m; bpw |= bp << 4;
        }
        a0 = n0; a1 = n1; a2 = n2;
        vbp |= (unsigned long long)bpw << (6 * j);
      }
    }
    float g0 = __shfl(a0, 63, 64), g1 = __shfl(a1, 63, 64), g2 = __shfl(a2, 63, 64);
    int init_tag = 0; float mx = g0;
    if (g1 > mx) { mx = g1; init_tag = 1; }
    if (g2 > mx) { mx = g2; init_tag = 2; }

    unsigned long long nb = shfl_down_u64(vbp, 1);
    int ht[8];
#pragma unroll
    for (int j = 0; j < 8; ++j) {
      int t = 8 * lane + j;
      int h = 0x24;
      if (t < L - 1) h = (j < 7) ? (int)((vbp >> (6 * (j + 1))) & 63ULL) : (int)(nb & 63ULL);
      ht[j] = h;
    }
    int F = 0x24;
#pragma unroll
    for (int j = 7; j >= 0; --j) F = map_compose(ht[j], F);
    int S2 = F;
#pragma unroll
    for (int s = 1; s < 64; s <<= 1) {
      int D = __shfl_down(S2, s, 64);
      if (lane + s < 64) S2 = map_compose(S2, D);
    }
    int tail = __shfl_down(S2, 1, 64);
    if (lane == 63) tail = 0x24;
    int cur = (tail >> (2 * init_tag)) & 3;
    int tags[8];
#pragma unroll
    for (int j = 7; j >= 0; --j) {
      cur = (ht[j] >> (2 * cur)) & 3;
      int t = 8 * lane + j;
      tags[j] = (t < L) ? cur : 0;
    }
    float4 o0, o1;
    o0.x = (float)tags[0]; o0.y = (float)tags[1]; o0.z = (float)tags[2]; o0.w = (float)tags[3];
    o1.x = (float)tags[4]; o1.y = (float)tags[5]; o1.z = (float)tags[6]; o1.w = (float)tags[7];
    float4* op = (float4*)(out + (size_t)b * 512 + lane * 8);
    op[0] = o0; op[1] = o1;
  }
}

extern "C" void kernel_launch(void* const* d_in, const int* in_sizes, int n_in,
                              void* d_out, int out_size, void* d_ws, size_t ws_size,
                              hipStream_t stream) {
  const float* hidden = (const float*)d_in[0];
  const float* wsub   = (const float*)d_in[1];
  const float* Wc     = (const float*)d_in[2];
  const float* bc     = (const float*)d_in[3];
  const float* Wd     = (const float*)d_in[4];
  const float* bd     = (const float*)d_in[5];
  const float* trans  = (const float*)d_in[6];
  const int*   tgt    = (const int*)d_in[7];

  float* ws     = (float*)d_ws;
  float* WeffT  = ws;
  float* beff   = ws + 4608;
  float* logits = ws + 4624;
  float* out    = (float*)d_out;

  hipLaunchKernelGGL(k_weff,   dim3(385), dim3(256), 0, stream, Wc, bc, Wd, bd, WeffT, beff);
  hipLaunchKernelGGL(k_logits, dim3(512), dim3(256), 0, stream, hidden, wsub, WeffT, beff, logits);
  hipLaunchKernelGGL(k_crf,    dim3(32),  dim3(128), 0, stream, logits, trans, tgt, out);
}

// Round 5
// 143.430 us; speedup vs baseline: 1.5550x; 1.0087x over previous
//
#include <hip/hip_runtime.h>
#include <cstdint>
#include <cstddef>

// B=32, S=512, D=768, K=3
// ws layout (floats):
//   [0, 4608)        WeffT (3 x 1536, column-major: WeffT[k*1536 + r])
//   [4608, 4611)     beff (3)
//   [4624, 53776)    logits (32*512*3)

#define DF 768
#define DX 1536
#define NINF 1e30f

__device__ __forceinline__ float lse3(float x, float y, float z) {
  float m = fmaxf(x, fmaxf(y, z));
  return m + __logf(__expf(x - m) + __expf(y - m) + __expf(z - m));
}

// map composition over {0,1,2}: r(x) = a(b(x)); maps packed 2 bits/entry
__device__ __forceinline__ int map_compose(int a, int b) {
  int r0 = (a >> (2 * (b & 3))) & 3;
  int r1 = (a >> (2 * ((b >> 2) & 3))) & 3;
  int r2 = (a >> (2 * ((b >> 4) & 3))) & 3;
  return r0 | (r1 << 2) | (r2 << 4);
}

__device__ __forceinline__ float sel3(int k, float x0, float x1, float x2) {
  return (k == 1) ? x1 : ((k == 2) ? x2 : x0);
}

__device__ __forceinline__ unsigned long long shfl_down_u64(unsigned long long v, int d) {
  int lo = __shfl_down((int)(unsigned int)(v & 0xffffffffULL), d, 64);
  int hi = __shfl_down((int)(unsigned int)(v >> 32), d, 64);
  return ((unsigned long long)(unsigned int)hi << 32) | (unsigned long long)(unsigned int)lo;
}

// ---------- Kernel A: collapse weights (transposed output) ----------
__global__ __launch_bounds__(256) void k_weff(
    const float* __restrict__ Wc, const float* __restrict__ bc,
    const float* __restrict__ Wd, const float* __restrict__ bd,
    float* __restrict__ WeffT, float* __restrict__ beff) {
  int lane = threadIdx.x & 63;
  int wv = threadIdx.x >> 6;
  int r = blockIdx.x * 4 + wv;
  if (r > DX) return;
  const float* src = (r < DX) ? (Wc + (size_t)r * DF) : bc;
  float a0 = 0.f, a1 = 0.f, a2 = 0.f;
#pragma unroll
  for (int it = 0; it < 12; ++it) {
    int f = lane + 64 * it;
    float w = src[f];
    const float* wd = Wd + f * 3;
    a0 += w * wd[0]; a1 += w * wd[1]; a2 += w * wd[2];
  }
#pragma unroll
  for (int off = 32; off; off >>= 1) {
    a0 += __shfl_xor(a0, off, 64);
    a1 += __shfl_xor(a1, off, 64);
    a2 += __shfl_xor(a2, off, 64);
  }
  if (lane == 0) {
    if (r < DX) {
      WeffT[0 * DX + r] = a0; WeffT[1 * DX + r] = a1; WeffT[2 * DX + r] = a2;
    } else {
      beff[0] = a0 + bd[0]; beff[1] = a1 + bd[1]; beff[2] = a2 + bd[2];
    }
  }
}

// ---------- Kernel B: logits, wave-private double-buffered LDS pipeline ----------
__global__ __launch_bounds__(256) void k_logits(
    const float* __restrict__ hidden, const float* __restrict__ wsub,
    const float* __restrict__ WeffT, const float* __restrict__ beff,
    float* __restrict__ logits) {
  __shared__ float smem[4 * 2 * 1536];  // 48 KB
  const int lane = threadIdx.x & 63;
  const int wv = threadIdx.x >> 6;

  float4 wr[3][6];
  {
    const float4* wt4 = (const float4*)WeffT;
#pragma unroll
    for (int k = 0; k < 3; ++k)
#pragma unroll
      for (int c = 0; c < 6; ++c)
        wr[k][c] = wt4[k * 384 + 64 * c + lane];
  }
  const float b0 = beff[0], b1 = beff[1], b2 = beff[2];

  float* mybuf = smem + wv * 3072;
  const int slot = blockIdx.x * 4 + wv;

#define STAGE(ROW, BUF)                                                              \
  do {                                                                               \
    const float* hsrc_ = hidden + (size_t)(ROW)*DF + lane * 4;                       \
    const float* ssrc_ = wsub + (size_t)(ROW)*DF + lane * 4;                         \
    float* l_ = mybuf + (BUF)*1536;                                                  \
    _Pragma("unroll")                                                                \
    for (int c_ = 0; c_ < 3; ++c_) {                                                 \
      __builtin_amdgcn_global_load_lds(                                              \
          (const __attribute__((address_space(1))) void*)(hsrc_ + c_ * 256),         \
          (__attribute__((address_space(3))) void*)(l_ + c_ * 256), 16, 0, 0);       \
      __builtin_amdgcn_global_load_lds(                                              \
          (const __attribute__((address_space(1))) void*)(ssrc_ + c_ * 256),         \
          (__attribute__((address_space(3))) void*)(l_ + 768 + c_ * 256), 16, 0, 0); \
    }                                                                                \
  } while (0)

  STAGE(slot, 0);
#pragma unroll
  for (int p = 0; p < 8; ++p) {
    if (p < 7) {
      STAGE(slot + (p + 1) * 2048, (p + 1) & 1);
      __builtin_amdgcn_s_waitcnt(0xF76);  // vmcnt(6)
    } else {
      __builtin_amdgcn_s_waitcnt(0xF70);  // vmcnt(0)
    }
    __builtin_amdgcn_sched_barrier(0);
    const float4* xb = (const float4*)(mybuf + (p & 1) * 1536);
    float a0 = 0.f, a1 = 0.f, a2 = 0.f;
#pragma unroll
    for (int c = 0; c < 6; ++c) {
      float4 v = xb[64 * c + lane];
      a0 += v.x * wr[0][c].x + v.y * wr[0][c].y + v.z * wr[0][c].z + v.w * wr[0][c].w;
      a1 += v.x * wr[1][c].x + v.y * wr[1][c].y + v.z * wr[1][c].z + v.w * wr[1][c].w;
      a2 += v.x * wr[2][c].x + v.y * wr[2][c].y + v.z * wr[2][c].z + v.w * wr[2][c].w;
    }
#pragma unroll
    for (int s = 32; s; s >>= 1) {
      a0 += __shfl_xor(a0, s, 64);
      a1 += __shfl_xor(a1, s, 64);
      a2 += __shfl_xor(a2, s, 64);
    }
    if (lane == 0) {
      float* o = logits + (size_t)(slot + p * 2048) * 3;
      o[0] = a0 + b0; o[1] = a1 + b1; o[2] = a2 + b2;
    }
  }
#undef STAGE
}

// ---------- Kernel C: CRF parallel semiring scan — fully hand-unrolled ----------
// Every array subscript is a compile-time literal (macros take literal j), so
// SROA cannot be defeated: R3/R4 kept VGPR_Count=36 because the 8-iteration
// compose loops didn't unroll, leaving lg[3*j+k] dynamically indexed ->
// scratch. This version has zero runtime-variable indexing.
__global__ __launch_bounds__(128) void k_crf(
    const float* __restrict__ logits, const float* __restrict__ trans,
    const int* __restrict__ tgt, float* __restrict__ out) {
  const int b = blockIdx.x;
  const int lane = threadIdx.x & 63;
  const int wv = threadIdx.x >> 6;
  const float* lrow = logits + (size_t)b * 1536;

  float lg[24];
  {
    const float4* l4 = (const float4*)(lrow + lane * 24);
    float4 v0 = l4[0], v1 = l4[1], v2 = l4[2], v3 = l4[3], v4 = l4[4], v5 = l4[5];
    lg[0] = v0.x; lg[1] = v0.y; lg[2] = v0.z; lg[3] = v0.w;
    lg[4] = v1.x; lg[5] = v1.y; lg[6] = v1.z; lg[7] = v1.w;
    lg[8] = v2.x; lg[9] = v2.y; lg[10] = v2.z; lg[11] = v2.w;
    lg[12] = v3.x; lg[13] = v3.y; lg[14] = v3.z; lg[15] = v3.w;
    lg[16] = v4.x; lg[17] = v4.y; lg[18] = v4.z; lg[19] = v4.w;
    lg[20] = v5.x; lg[21] = v5.y; lg[22] = v5.z; lg[23] = v5.w;
  }
  int tl0, tl1, tl2, tl3, tl4, tl5, tl6, tl7;
  {
    const int4* t4 = (const int4*)(tgt + (size_t)b * 512 + lane * 8);
    int4 u = t4[0], v = t4[1];
    tl0 = u.x; tl1 = u.y; tl2 = u.z; tl3 = u.w;
    tl4 = v.x; tl5 = v.y; tl6 = v.z; tl7 = v.w;
  }
  int cnt = (tl0 >= 1) + (tl1 >= 1) + (tl2 >= 1) + (tl3 >= 1) +
            (tl4 >= 1) + (tl5 >= 1) + (tl6 >= 1) + (tl7 >= 1);
#pragma unroll
  for (int s = 32; s; s >>= 1) cnt += __shfl_xor(cnt, s, 64);
  const int L = cnt;

  float T[9];
  T[0] = trans[0]; T[1] = trans[1]; T[2] = trans[2];
  T[3] = trans[3]; T[4] = trans[4]; T[5] = trans[5];
  T[6] = trans[6]; T[7] = trans[7]; T[8] = trans[8];
  float f0 = lrow[0], f1 = lrow[1], f2 = lrow[2];

  if (wv == 0) {
    // ---- unary + binary partial sums (select chains, literal indices) ----
    float part = 0.f;
    int tln = __shfl_down(tl0, 1, 64);
#define USTEP(j, TJ, NXT) {                                              \
    const int t_ = 8 * lane + (j);                                       \
    float u_ = sel3((TJ), lg[3*(j)+0], lg[3*(j)+1], lg[3*(j)+2]);        \
    if (t_ < L) part += u_;                                              \
    float r0_ = sel3((TJ), T[0], T[3], T[6]);                            \
    float r1_ = sel3((TJ), T[1], T[4], T[7]);                            \
    float r2_ = sel3((TJ), T[2], T[5], T[8]);                            \
    float b_ = sel3((NXT), r0_, r1_, r2_);                               \
    if (t_ < L - 1) part += b_; }
    USTEP(0, tl0, tl1) USTEP(1, tl1, tl2) USTEP(2, tl2, tl3) USTEP(3, tl3, tl4)
    USTEP(4, tl4, tl5) USTEP(5, tl5, tl6) USTEP(6, tl6, tl7) USTEP(7, tl7, tln)
#undef USTEP
#pragma unroll
    for (int s = 32; s; s >>= 1) part += __shfl_xor(part, s, 64);

    // ---- local (LSE,+) product over owned steps t in [1, idx] ----
    int idx = L - 1; if (idx < 0) idx = 0;
    float C[9] = {0.f, -NINF, -NINF, -NINF, 0.f, -NINF, -NINF, -NINF, 0.f};
#define CSTEP(j) {                                                       \
    const int t_ = 8 * lane + (j);                                       \
    if (t_ >= 1 && t_ <= idx) {                                          \
      const float m0_ = lg[3*(j)+0], m1_ = lg[3*(j)+1], m2_ = lg[3*(j)+2];\
      float r0_ = lse3(C[0]+T[0], C[1]+T[3], C[2]+T[6]) + m0_;           \
      float r1_ = lse3(C[0]+T[1], C[1]+T[4], C[2]+T[7]) + m1_;           \
      float r2_ = lse3(C[0]+T[2], C[1]+T[5], C[2]+T[8]) + m2_;           \
      float r3_ = lse3(C[3]+T[0], C[4]+T[3], C[5]+T[6]) + m0_;           \
      float r4_ = lse3(C[3]+T[1], C[4]+T[4], C[5]+T[7]) + m1_;           \
      float r5_ = lse3(C[3]+T[2], C[4]+T[5], C[5]+T[8]) + m2_;           \
      float r6_ = lse3(C[6]+T[0], C[7]+T[3], C[8]+T[6]) + m0_;           \
      float r7_ = lse3(C[6]+T[1], C[7]+T[4], C[8]+T[7]) + m1_;           \
      float r8_ = lse3(C[6]+T[2], C[7]+T[5], C[8]+T[8]) + m2_;           \
      C[0]=r0_; C[1]=r1_; C[2]=r2_; C[3]=r3_; C[4]=r4_;                  \
      C[5]=r5_; C[6]=r6_; C[7]=r7_; C[8]=r8_; } }
    CSTEP(0) CSTEP(1) CSTEP(2) CSTEP(3) CSTEP(4) CSTEP(5) CSTEP(6) CSTEP(7)
#undef CSTEP

    // ---- ordered butterfly reduction across 64 lanes ----
#define BSTAGE(s) {                                                      \
    float D0=__shfl_xor(C[0],(s),64), D1=__shfl_xor(C[1],(s),64),        \
          D2=__shfl_xor(C[2],(s),64), D3=__shfl_xor(C[3],(s),64),        \
          D4=__shfl_xor(C[4],(s),64), D5=__shfl_xor(C[5],(s),64),        \
          D6=__shfl_xor(C[6],(s),64), D7=__shfl_xor(C[7],(s),64),        \
          D8=__shfl_xor(C[8],(s),64);                                    \
    const bool hi_ = (lane & (s)) != 0;                                  \
    float A0=hi_?D0:C[0], A1=hi_?D1:C[1], A2=hi_?D2:C[2],                \
          A3=hi_?D3:C[3], A4=hi_?D4:C[4], A5=hi_?D5:C[5],                \
          A6=hi_?D6:C[6], A7=hi_?D7:C[7], A8=hi_?D8:C[8];                \
    float B0=hi_?C[0]:D0, B1=hi_?C[1]:D1, B2=hi_?C[2]:D2,                \
          B3=hi_?C[3]:D3, B4=hi_?C[4]:D4, B5=hi_?C[5]:D5,                \
          B6=hi_?C[6]:D6, B7=hi_?C[7]:D7, B8=hi_?C[8]:D8;                \
    C[0]=lse3(A0+B0, A1+B3, A2+B6); C[1]=lse3(A0+B1, A1+B4, A2+B7);      \
    C[2]=lse3(A0+B2, A1+B5, A2+B8); C[3]=lse3(A3+B0, A4+B3, A5+B6);      \
    C[4]=lse3(A3+B1, A4+B4, A5+B7); C[5]=lse3(A3+B2, A4+B5, A5+B8);      \
    C[6]=lse3(A6+B0, A7+B3, A8+B6); C[7]=lse3(A6+B1, A7+B4, A8+B7);      \
    C[8]=lse3(A6+B2, A7+B5, A8+B8); }
    BSTAGE(1) BSTAGE(2) BSTAGE(4) BSTAGE(8) BSTAGE(16) BSTAGE(32)
#undef BSTAGE

    float al0 = lse3(f0 + C[0], f1 + C[3], f2 + C[6]);
    float al1 = lse3(f0 + C[1], f1 + C[4], f2 + C[7]);
    float al2 = lse3(f0 + C[2], f1 + C[5], f2 + C[8]);
    float log_norm = lse3(al0, al1, al2);
    if (L <= 0) log_norm = 0.f;
    if (lane == 0) out[16384 + b] = part - log_norm;
  } else {
    // ---- Viterbi: local (max,+) product ----
    float P[9] = {0.f, -NINF, -NINF, -NINF, 0.f, -NINF, -NINF, -NINF, 0.f};
#define PSTEP(j) {                                                       \
    const int t_ = 8 * lane + (j);                                       \
    if (t_ >= 1 && t_ < L) {                                             \
      const float m0_ = lg[3*(j)+0], m1_ = lg[3*(j)+1], m2_ = lg[3*(j)+2];\
      float r0_ = fmaxf(fmaxf(P[0]+T[0], P[1]+T[3]), P[2]+T[6]) + m0_;   \
      float r1_ = fmaxf(fmaxf(P[0]+T[1], P[1]+T[4]), P[2]+T[7]) + m1_;   \
      float r2_ = fmaxf(fmaxf(P[0]+T[2], P[1]+T[5]), P[2]+T[8]) + m2_;   \
      float r3_ = fmaxf(fmaxf(P[3]+T[0], P[4]+T[3]), P[5]+T[6]) + m0_;   \
      float r4_ = fmaxf(fmaxf(P[3]+T[1], P[4]+T[4]), P[5]+T[7]) + m1_;   \
      float r5_ = fmaxf(fmaxf(P[3]+T[2], P[4]+T[5]), P[5]+T[8]) + m2_;   \
      float r6_ = fmaxf(fmaxf(P[6]+T[0], P[7]+T[3]), P[8]+T[6]) + m0_;   \
      float r7_ = fmaxf(fmaxf(P[6]+T[1], P[7]+T[4]), P[8]+T[7]) + m1_;   \
      float r8_ = fmaxf(fmaxf(P[6]+T[2], P[7]+T[5]), P[8]+T[8]) + m2_;   \
      P[0]=r0_; P[1]=r1_; P[2]=r2_; P[3]=r3_; P[4]=r4_;                  \
      P[5]=r5_; P[6]=r6_; P[7]=r7_; P[8]=r8_; } }
    PSTEP(0) PSTEP(1) PSTEP(2) PSTEP(3) PSTEP(4) PSTEP(5) PSTEP(6) PSTEP(7)
#undef PSTEP

    // ---- inclusive Kogge-Stone prefix (earlier lane on the left) ----
#define KSTAGE(s) {                                                      \
    float D0=__shfl_up(P[0],(s),64), D1=__shfl_up(P[1],(s),64),          \
          D2=__shfl_up(P[2],(s),64), D3=__shfl_up(P[3],(s),64),          \
          D4=__shfl_up(P[4],(s),64), D5=__shfl_up(P[5],(s),64),          \
          D6=__shfl_up(P[6],(s),64), D7=__shfl_up(P[7],(s),64),          \
          D8=__shfl_up(P[8],(s),64);                                     \
    if (lane >= (s)) {                                                   \
      float r0_=fmaxf(fmaxf(D0+P[0], D1+P[3]), D2+P[6]);                 \
      float r1_=fmaxf(fmaxf(D0+P[1], D1+P[4]), D2+P[7]);                 \
      float r2_=fmaxf(fmaxf(D0+P[2], D1+P[5]), D2+P[8]);                 \
      float r3_=fmaxf(fmaxf(D3+P[0], D4+P[3]), D5+P[6]);                 \
      float r4_=fmaxf(fmaxf(D3+P[1], D4+P[4]), D5+P[7]);                 \
      float r5_=fmaxf(fmaxf(D3+P[2], D4+P[5]), D5+P[8]);                 \
      float r6_=fmaxf(fmaxf(D6+P[0], D7+P[3]), D8+P[6]);                 \
      float r7_=fmaxf(fmaxf(D6+P[1], D7+P[4]), D8+P[7]);                 \
      float r8_=fmaxf(fmaxf(D6+P[2], D7+P[5]), D8+P[8]);                 \
      P[0]=r0_; P[1]=r1_; P[2]=r2_; P[3]=r3_; P[4]=r4_;                  \
      P[5]=r5_; P[6]=r6_; P[7]=r7_; P[8]=r8_; } }
    KSTAGE(1) KSTAGE(2) KSTAGE(4) KSTAGE(8) KSTAGE(16) KSTAGE(32)
#undef KSTAGE

    // exclusive prefix -> alpha entering this lane's first step
    float E0=__shfl_up(P[0],1,64), E1=__shfl_up(P[1],1,64), E2=__shfl_up(P[2],1,64),
          E3=__shfl_up(P[3],1,64), E4=__shfl_up(P[4],1,64), E5=__shfl_up(P[5],1,64),
          E6=__shfl_up(P[6],1,64), E7=__shfl_up(P[7],1,64), E8=__shfl_up(P[8],1,64);
    if (lane == 0) {
      E0 = 0.f; E1 = -NINF; E2 = -NINF;
      E3 = -NINF; E4 = 0.f; E5 = -NINF;
      E6 = -NINF; E7 = -NINF; E8 = 0.f;
    }
    float a0 = fmaxf(fmaxf(f0 + E0, f1 + E3), f2 + E6);
    float a1 = fmaxf(fmaxf(f0 + E1, f1 + E4), f2 + E7);
    float a2 = fmaxf(fmaxf(f0 + E2, f1 + E5), f2 + E8);

    // ---- per-step backpointers (first-index argmax ties) ----
    unsigned long long vbp = 0ULL;
#define VSTEP(j) {                                                       \
    const int t_ = 8 * lane + (j);                                       \
    if (t_ >= 1 && t_ < L) {                                             \
      int bpw_ = 0; float n0_, n1_, n2_;                                 \
      { int bp_ = 0; float m_ = a0 + T[0];                               \
        float c1_ = a1 + T[3]; if (c1_ > m_) { m_ = c1_; bp_ = 1; }      \
        float c2_ = a2 + T[6]; if (c2_ > m_) { m_ = c2_; bp_ = 2; }      \
        n0_ = lg[3*(j)+0] + m_; bpw_ |= bp_; }                           \
      { int bp_ = 0; float m_ = a0 + T[1];                               \
        float c1_ = a1 + T[4]; if (c1_ > m_) { m_ = c1_; bp_ = 1; }      \
        float c2_ = a2 + T[7]; if (c2_ > m_) { m_ = c2_; bp_ = 2; }      \
        n1_ = lg[3*(j)+1] + m_; bpw_ |= bp_ << 2; }                      \
      { int bp_ = 0; float m_ = a0 + T[2];                               \
        float c1_ = a1 + T[5]; if (c1_ > m_) { m_ = c1_; bp_ = 1; }      \
        float c2_ = a2 + T[8]; if (c2_ > m_) { m_ = c2_; bp_ = 2; }      \
        n2_ = lg[3*(j)+2] + m_; bpw_ |= bp_ << 4; }                      \
      a0 = n0_; a1 = n1_; a2 = n2_;                                      \
      vbp |= (unsigned long long)bpw_ << (6 * (j)); } }
    VSTEP(0) VSTEP(1) VSTEP(2) VSTEP(3) VSTEP(4) VSTEP(5) VSTEP(6) VSTEP(7)
#undef VSTEP

    float g0 = __shfl(a0, 63, 64), g1 = __shfl(a1, 63, 64), g2 = __shfl(a2, 63, 64);
    int init_tag = 0; float mx = g0;
    if (g1 > mx) { mx = g1; init_tag = 1; }
    if (g2 > mx) { mx = g2; init_tag = 2; }

    // ---- backtrace maps h_t: tag_{t+1} -> tag_t (identity 0x24 if t >= L-1)
    unsigned long long nb = shfl_down_u64(vbp, 1);
#define HDEF(j, EXPR) int h##j; {                                        \
    const int t_ = 8 * lane + (j);                                       \
    h##j = (t_ < L - 1) ? (EXPR) : 0x24; }
    HDEF(0, (int)((vbp >> 6) & 63ULL))
    HDEF(1, (int)((vbp >> 12) & 63ULL))
    HDEF(2, (int)((vbp >> 18) & 63ULL))
    HDEF(3, (int)((vbp >> 24) & 63ULL))
    HDEF(4, (int)((vbp >> 30) & 63ULL))
    HDEF(5, (int)((vbp >> 36) & 63ULL))
    HDEF(6, (int)((vbp >> 42) & 63ULL))
    HDEF(7, (int)(nb & 63ULL))
#undef HDEF

    int F = 0x24;
    F = map_compose(h7, F); F = map_compose(h6, F); F = map_compose(h5, F);
    F = map_compose(h4, F); F = map_compose(h3, F); F = map_compose(h2, F);
    F = map_compose(h1, F); F = map_compose(h0, F);

    int S2 = F;
#define SSTAGE(s) { int D_ = __shfl_down(S2, (s), 64);                   \
    if (lane + (s) < 64) S2 = map_compose(S2, D_); }
    SSTAGE(1) SSTAGE(2) SSTAGE(4) SSTAGE(8) SSTAGE(16) SSTAGE(32)
#undef SSTAGE
    int tail = __shfl_down(S2, 1, 64);
    if (lane == 63) tail = 0x24;
    int cur = (tail >> (2 * init_tag)) & 3;

    float o0x, o0y, o0z, o0w, o1x, o1y, o1z, o1w;
#define TSTEP(j, VAR) {                                                  \
    cur = (h##j >> (2 * cur)) & 3;                                       \
    const int t_ = 8 * lane + (j);                                       \
    VAR = (t_ < L) ? (float)cur : 0.f; }
    TSTEP(7, o1w) TSTEP(6, o1z) TSTEP(5, o1y) TSTEP(4, o1x)
    TSTEP(3, o0w) TSTEP(2, o0z) TSTEP(1, o0y) TSTEP(0, o0x)
#undef TSTEP
    float4 o0, o1;
    o0.x = o0x; o0.y = o0y; o0.z = o0z; o0.w = o0w;
    o1.x = o1x; o1.y = o1y; o1.z = o1z; o1.w = o1w;
    float4* op = (float4*)(out + (size_t)b * 512 + lane * 8);
    op[0] = o0; op[1] = o1;
  }
}

extern "C" void kernel_launch(void* const* d_in, const int* in_sizes, int n_in,
                              void* d_out, int out_size, void* d_ws, size_t ws_size,
                              hipStream_t stream) {
  const float* hidden = (const float*)d_in[0];
  const float* wsub   = (const float*)d_in[1];
  const float* Wc     = (const float*)d_in[2];
  const float* bc     = (const float*)d_in[3];
  const float* Wd     = (const float*)d_in[4];
  const float* bd     = (const float*)d_in[5];
  const float* trans  = (const float*)d_in[6];
  const int*   tgt    = (const int*)d_in[7];

  float* ws     = (float*)d_ws;
  float* WeffT  = ws;
  float* beff   = ws + 4608;
  float* logits = ws + 4624;
  float* out    = (float*)d_out;

  hipLaunchKernelGGL(k_weff,   dim3(385), dim3(256), 0, stream, Wc, bc, Wd, bd, WeffT, beff);
  hipLaunchKernelGGL(k_logits, dim3(512), dim3(256), 0, stream, hidden, wsub, WeffT, beff, logits);
  hipLaunchKernelGGL(k_crf,    dim3(32),  dim3(128), 0, stream, logits, trans, tgt, out);
}